// Round 17
// baseline (54.538 us; speedup 1.0000x reference)
//
#include <hip/hip_runtime.h>

// SparseMaskedLinear: out[b,co] = bias[co] + sum_e in[b,ci_e]*w_e  (B=64, dims 2000)
// Dense reformulation: W[ci][co] = sum w_e;  out = in[:, :2000] @ W + bias.
// Round-17: (1) 4-row bins (500) -> bin_build 500 blocks @ 32KB tile = 2/CU
// (was 250 blocks @ 62.5KB = <1/CU, 25% occupancy). (2) SLICES 16->8 with
// 4-chunk software-pipelined gemm -> partial traffic halved. Scatter keeps
// R14's proven staged-flush form (SCAP 16, cp multiple of 8 keeps uint4 groups
// fully written; pad sentinel bit31).
// 4 dispatches: scatter -> bin_build -> gemm -> reduce.

#define ROWSB 4
#define NB 512                 // hist/counts rows; row NB-1 = overflow counts
#define NSEGP 512              // counts row length (nseg <= 512)
#define SCAP 16                // slab capacity per (bin,blk); mean 8.2, +2.7 sigma
#define OVB 32                 // per-block overflow slab capacity
#define E_PT 8
#define TPB_SC 512
#define SEGX (TPB_SC * E_PT)   // 4096 edges per scatter block
#define PAD32 0xFFFFFFFFu      // bit 31 set = pad

#define TILE_O 64
#define KS 64
#define SLICES 8
#define NCH 4                  // K-chunks per slice: SLICES*NCH*KS = 2048
#define PSTRIDE 2048

// ---- Phase 1: deterministic scatter, 4B records, 4-row bins. Reg-preload 8
// edges (MLP), LDS rank, staged flush of used 32B granules; bin-major counts.
__global__ __launch_bounds__(TPB_SC) void smw_scatter14(
    const int* __restrict__ mask, const float* __restrict__ wgt,
    unsigned* __restrict__ binned, int* __restrict__ counts,
    int2* __restrict__ ovfblk, int n_edges, int krows, int nbins, int nseg) {
    __shared__ int hist[NB];
    __shared__ int sflag;
    __shared__ int ovfc;
    extern __shared__ unsigned stage32[];      // nbins * SCAP u32 (<= 32768 B)
    const int tid = threadIdx.x;
    const int blk = blockIdx.x;
    const long long e0 = (long long)blk * SEGX;
    if (tid < NB) hist[tid] = 0;
    if (tid == 0) ovfc = 0;
    if (tid < 64) {
        unsigned v = (tid < n_edges) ? ((const unsigned*)mask)[2 * tid + 1] : 0u;
        unsigned long long bal = __ballot(v != 0u);
        if (tid == 0) sflag = (bal == 0ull) ? 1 : 0;   // high words all zero => int64
    }
    __syncthreads();
    const bool is64 = (sflag != 0);

    // load phase: 8 independent edges into registers (deep vmcnt pipeline)
    int ci[E_PT], co[E_PT]; float wv[E_PT];
    if (is64) {
        #pragma unroll
        for (int i = 0; i < E_PT; ++i) {
            long long e = e0 + (long long)i * TPB_SC + tid;
            ci[i] = -1; co[i] = 0;
            if (e < n_edges) { int4 mm = ((const int4*)mask)[e]; ci[i] = mm.x; co[i] = mm.z; }
        }
    } else {
        #pragma unroll
        for (int i = 0; i < E_PT; ++i) {
            long long e = e0 + (long long)i * TPB_SC + tid;
            ci[i] = -1; co[i] = 0;
            if (e < n_edges) { int2 mm = ((const int2*)mask)[e]; ci[i] = mm.x; co[i] = mm.y; }
        }
    }
    #pragma unroll
    for (int i = 0; i < E_PT; ++i) {
        long long e = e0 + (long long)i * TPB_SC + tid;
        wv[i] = (e < n_edges) ? wgt[e] : 0.0f;
    }

    // rank + stage phase (bf16 RNE pack; key14 = (ci&3)<<11 | co)
    #pragma unroll
    for (int i = 0; i < E_PT; ++i) {
        if ((unsigned)ci[i] < (unsigned)krows) {
            int b = ci[i] >> 2;                    // 4 rows per bin
            int r = atomicAdd(&hist[b], 1);        // LDS rank
            if (r < SCAP) {
                unsigned u  = __float_as_uint(wv[i]);
                unsigned bf = (u + 0x7FFFu + ((u >> 16) & 1u)) >> 16;   // RNE
                unsigned key = (((unsigned)(ci[i] & 3)) << 11) | (unsigned)(co[i] & 0x7FF);
                stage32[b * SCAP + r] = (key << 16) | bf;
            } else {                               // rare tail (~600 records total)
                int j = atomicAdd(&ovfc, 1);
                if (j < OVB)
                    ovfblk[blk * OVB + j] =
                        make_int2((ci[i] << 16) | (co[i] & 0xFFFF),
                                  __float_as_int(wv[i]));
            }
        }
    }
    __syncthreads();
    // flush: 32 groups x 16 lanes, used 32B granules only (cp in {0,8,16})
    const int grp = tid >> 4;
    const int ln  = tid & 15;
    for (int b = grp; b < nbins; b += (TPB_SC / 16)) {
        int c = hist[b]; if (c > SCAP) c = SCAP;
        int cp = (c + 7) & ~7;
        long long base = ((long long)b * nseg + blk) * SCAP;   // bin-major slabs
        if (ln < cp)
            binned[base + ln] = (ln < c) ? stage32[b * SCAP + ln] : PAD32;
        if (ln == 0) counts[b * NSEGP + blk] = cp;
    }
    if (tid == 0) {
        int oc = ovfc; if (oc > OVB) oc = OVB;
        counts[(NB - 1) * NSEGP + blk] = oc;       // ovf row, written EVERY call
    }
}

// ---- Phase 2: per-bin exclusive build of 4 W-rows (32KB tile -> 2 blocks/CU,
// 500 blocks). One predicated uint4 per 4-lane subgroup per slab (cp<=16).
__global__ __launch_bounds__(512) void smw_bin_build11(
    const unsigned* __restrict__ binned, const int* __restrict__ counts,
    const int2* __restrict__ ovfblk, float* __restrict__ W,
    int out_f, int krows, int nseg) {
    extern __shared__ float tile[];                 // ROWSB * out_f floats (32KB)
    const int tid = threadIdx.x;
    const int bin = blockIdx.x;
    const int tile_elems = ROWSB * out_f;
    {
        float4* t4 = (float4*)tile;
        int n4 = tile_elems >> 2;
        for (int t = tid; t < n4; t += 512) t4[t] = make_float4(0.f, 0.f, 0.f, 0.f);
    }
    __syncthreads();
    const int grp = tid >> 2;                      // 128 subgroups of 4 lanes
    const int ln4 = tid & 3;
    for (int s = grp; s < nseg; s += 128) {
        int cp = counts[bin * NSEGP + s];          // bin-major: contiguous in s
        if (ln4 * 4 < cp) {                        // cp in {0,8,16}: uint4-safe
            uint4 q = ((const uint4*)(binned + ((long long)bin * nseg + s) * SCAP))[ln4];
            #pragma unroll
            for (int t = 0; t < 4; ++t) {
                unsigned r = (t == 0) ? q.x : (t == 1) ? q.y : (t == 2) ? q.z : q.w;
                if ((int)r >= 0) {                 // bit31 clear = valid
                    unsigned key = r >> 16;
                    atomicAdd(&tile[(int)(key >> 11) * out_f + (int)(key & 0x7FFu)],
                              __uint_as_float((r & 0xFFFFu) << 16));
                }
            }
        }
    }
    // per-block overflow slabs (full f32)
    for (int s = tid; s < nseg; s += 512) {
        int oc = counts[(NB - 1) * NSEGP + s];
        for (int j = 0; j < oc; ++j) {
            int2 r = ovfblk[s * OVB + j];
            int ci = ((unsigned)r.x) >> 16;
            if ((ci >> 2) == bin)
                atomicAdd(&tile[(ci & 3) * out_f + (r.x & 0xFFFF)],
                          __int_as_float(r.y));
        }
    }
    __syncthreads();
    #pragma unroll
    for (int r = 0; r < ROWSB; ++r) {
        int row = bin * ROWSB + r;
        if (row >= krows) break;
        float* dst = W + (long long)row * out_f;
        const float* s = tile + r * out_f;
        for (int c = tid * 4; c < out_f; c += 2048)
            *(float4*)&dst[c] = *(const float4*)&s[c];
    }
}

// ---- staging helpers for gemm (static unroll, register-resident)
__device__ __forceinline__ void smw_load_a(float4 (&r)[4], const float* __restrict__ A,
                                           int k0, int in_features, int krows,
                                           int Bsz, int tid) {
    #pragma unroll
    for (int t = 0; t < 4; ++t) {
        int idx = t * 256 + tid;
        int b = idx >> 4;
        int c4 = (idx & 15) * 4;
        int gi = k0 + c4;
        float4 v = make_float4(0.f, 0.f, 0.f, 0.f);
        if (b < Bsz) {
            const float* src = A + (long long)b * in_features + gi;
            if (gi + 3 < krows) v = *(const float4*)src;
            else {
                if (gi + 0 < krows) v.x = src[0];
                if (gi + 1 < krows) v.y = src[1];
                if (gi + 2 < krows) v.z = src[2];
                if (gi + 3 < krows) v.w = src[3];
            }
        }
        r[t] = v;
    }
}

__device__ __forceinline__ void smw_load_w(float4 (&r)[4], const float* __restrict__ W,
                                           int k0, int o_base, int out_f, int krows,
                                           int tid) {
    #pragma unroll
    for (int t = 0; t < 4; ++t) {
        int idx = t * 256 + tid;
        int rr = idx >> 4;
        int c4 = (idx & 15) * 4;
        int gi = k0 + rr;
        int go = o_base + c4;
        float4 v = make_float4(0.f, 0.f, 0.f, 0.f);
        if (gi < krows) {
            const float* src = W + (long long)gi * out_f + go;
            if (go + 3 < out_f) v = *(const float4*)src;
            else {
                if (go + 0 < out_f) v.x = src[0];
                if (go + 1 < out_f) v.y = src[1];
                if (go + 2 < out_f) v.z = src[2];
                if (go + 3 < out_f) v.w = src[3];
            }
        }
        r[t] = v;
    }
}

// ---- Phase 3: GEMM, 4-chunk software pipeline (issue chunk i+2 under i+1).
__global__ __launch_bounds__(256) void smw_gemm7(
    const float* __restrict__ A, const float* __restrict__ W,
    float* __restrict__ partial, int in_features, int out_f, int krows, int Bsz) {
    __shared__ float As[64][KS + 4];
    __shared__ float Ws[KS][TILE_O];
    const int tid = threadIdx.x;
    const int tx = tid & 15;
    const int ty = tid >> 4;
    const int o_base = blockIdx.x * TILE_O;
    const int k0 = blockIdx.y * (NCH * KS);

    float4 ra[4], rw[4];
    smw_load_a(ra, A, k0, in_features, krows, Bsz, tid);
    smw_load_w(rw, W, k0, o_base, out_f, krows, tid);
    #pragma unroll
    for (int t = 0; t < 4; ++t) {
        int idx = t * 256 + tid;
        *(float4*)&As[idx >> 4][(idx & 15) * 4] = ra[t];
        *(float4*)&Ws[idx >> 4][(idx & 15) * 4] = rw[t];
    }
    smw_load_a(ra, A, k0 + KS, in_features, krows, Bsz, tid);
    smw_load_w(rw, W, k0 + KS, o_base, out_f, krows, tid);
    __syncthreads();

    float acc[4][4] = {};
    #pragma unroll
    for (int ch = 0; ch < NCH; ++ch) {
        #pragma unroll 8
        for (int i = 0; i < KS; ++i) {
            float4 w4 = *(const float4*)&Ws[i][tx * 4];
            float a[4];
            #pragma unroll
            for (int r = 0; r < 4; ++r) a[r] = As[ty * 4 + r][i];
            #pragma unroll
            for (int r = 0; r < 4; ++r) {
                acc[r][0] += a[r] * w4.x;
                acc[r][1] += a[r] * w4.y;
                acc[r][2] += a[r] * w4.z;
                acc[r][3] += a[r] * w4.w;
            }
        }
        if (ch < NCH - 1) {
            __syncthreads();                       // all lanes done reading LDS
            #pragma unroll
            for (int t = 0; t < 4; ++t) {
                int idx = t * 256 + tid;
                *(float4*)&As[idx >> 4][(idx & 15) * 4] = ra[t];
                *(float4*)&Ws[idx >> 4][(idx & 15) * 4] = rw[t];
            }
            if (ch < NCH - 2) {
                smw_load_a(ra, A, k0 + (ch + 2) * KS, in_features, krows, Bsz, tid);
                smw_load_w(rw, W, k0 + (ch + 2) * KS, o_base, out_f, krows, tid);
            }
            __syncthreads();
        }
    }

    float* P = partial + (long long)blockIdx.y * 64 * PSTRIDE;
    #pragma unroll
    for (int r = 0; r < 4; ++r) {
        int b = ty * 4 + r;
        if (b < Bsz)
            *(float4*)&P[(long long)b * PSTRIDE + o_base + tx * 4] =
                make_float4(acc[r][0], acc[r][1], acc[r][2], acc[r][3]);
    }
}

// ---- Phase 4: out = bias + sum_s partial[s]  (float4 lanes)
__global__ void smw_reduce4(const float* __restrict__ partial,
                            const float* __restrict__ bias,
                            float* __restrict__ out, int out_f, int Bsz, int total4) {
    int idx = blockIdx.x * blockDim.x + threadIdx.x;
    if (idx >= total4) return;
    const int of4 = out_f >> 2;
    int b = idx / of4, o4 = idx - b * of4;
    const float4* B4 = (const float4*)bias;
    const float4* P4 = (const float4*)partial;
    float4 acc = B4[o4];
    #pragma unroll
    for (int s = 0; s < SLICES; ++s) {
        float4 v = P4[((long long)s * 64 + b) * (PSTRIDE >> 2) + o4];
        acc.x += v.x; acc.y += v.y; acc.z += v.z; acc.w += v.w;
    }
    ((float4*)out)[idx] = acc;
}

// ================= fallback path (round-1, known-good, needs only 16 MB ws) ==
__global__ void smw_detect(const unsigned int* __restrict__ m, int* __restrict__ flag) {
    if (blockIdx.x == 0 && threadIdx.x == 0) {
        unsigned int orv = 0u;
        for (int k = 0; k < 64; ++k) orv |= m[2 * k + 1];
        *flag = (orv == 0u) ? 1 : 0;
    }
}

__global__ void smw_build_fb(const int* __restrict__ mask, const float* __restrict__ wgt,
                             float* __restrict__ W, const int* __restrict__ flag,
                             int n_edges, int out_f) {
    int e = blockIdx.x * blockDim.x + threadIdx.x;
    if (e >= n_edges) return;
    int ci, co;
    if (*flag) {
        const long long* m64 = (const long long*)mask;
        ci = (int)m64[2 * (long long)e];
        co = (int)m64[2 * (long long)e + 1];
    } else {
        ci = mask[2 * e]; co = mask[2 * e + 1];
    }
    atomicAdd(&W[(long long)ci * out_f + co], wgt[e]);
}

__global__ void smw_init_out_fb(float* __restrict__ out, const float* __restrict__ bias,
                                int total, int out_f) {
    int idx = blockIdx.x * blockDim.x + threadIdx.x;
    if (idx < total) out[idx] = bias[idx % out_f];
}

__global__ __launch_bounds__(256) void smw_gemm_fb(
    const float* __restrict__ A, const float* __restrict__ W,
    float* __restrict__ out, int in_features, int out_f, int krows,
    int n_chunks, int Bsz) {
    __shared__ float As[64][36];
    __shared__ float Ws[32][64];
    const int tid = threadIdx.x;
    const int tx = tid & 15;
    const int ty = tid >> 4;
    const int o_base = blockIdx.x * 64;
    float acc[4][4] = {};
    for (int c = blockIdx.y; c < n_chunks; c += 8) {
        const int i0 = c * 32;
        __syncthreads();
        #pragma unroll
        for (int k = 0; k < 8; ++k) {
            int idx = k * 256 + tid;
            int i = idx & 31;
            int b = idx >> 5;
            float v = 0.0f;
            int gi = i0 + i;
            if (b < Bsz && gi < in_features) v = A[(long long)b * in_features + gi];
            As[b][i] = v;
        }
        #pragma unroll
        for (int k = 0; k < 8; ++k) {
            int idx = k * 256 + tid;
            int o = idx & 63;
            int i = idx >> 6;
            int gi = i0 + i;
            int go = o_base + o;
            Ws[i][o] = (gi < krows && go < out_f) ? W[(long long)gi * out_f + go] : 0.0f;
        }
        __syncthreads();
        #pragma unroll
        for (int i = 0; i < 32; ++i) {
            float4 w4 = *(const float4*)(&Ws[i][tx * 4]);
            float a[4];
            #pragma unroll
            for (int r = 0; r < 4; ++r) a[r] = As[ty * 4 + r][i];
            #pragma unroll
            for (int r = 0; r < 4; ++r) {
                acc[r][0] += a[r] * w4.x;
                acc[r][1] += a[r] * w4.y;
                acc[r][2] += a[r] * w4.z;
                acc[r][3] += a[r] * w4.w;
            }
        }
    }
    #pragma unroll
    for (int r = 0; r < 4; ++r) {
        int b = ty * 4 + r;
        if (b >= Bsz) continue;
        #pragma unroll
        for (int cc = 0; cc < 4; ++cc) {
            int o = o_base + tx * 4 + cc;
            if (o < out_f) atomicAdd(&out[(long long)b * out_f + o], acc[r][cc]);
        }
    }
}

// =============================================================================
static inline size_t align_up(size_t x, size_t a) { return (x + a - 1) & ~(a - 1); }

extern "C" void kernel_launch(void* const* d_in, const int* in_sizes, int n_in,
                              void* d_out, int out_size, void* d_ws, size_t ws_size,
                              hipStream_t stream) {
    const float* input = (const float*)d_in[0];
    const int*   mask  = (const int*)d_in[1];
    const float* wgt   = (const float*)d_in[2];
    const float* bias  = (const float*)d_in[3];
    float* out = (float*)d_out;

    const int out_f   = in_sizes[3];            // 2000
    const int n_edges = in_sizes[2];            // 2,000,000
    const int Bsz     = out_size / out_f;       // 64
    const int in_features = in_sizes[0] / Bsz;  // 20000
    const int krows   = out_f;                  // ci values < out_f per problem spec
    const int nbins   = (krows + ROWSB - 1) / ROWSB;   // 500
    const int nseg    = (n_edges + SEGX - 1) / SEGX;   // 489
    const int n_ot    = (out_f + TILE_O - 1) / TILE_O; // 32

    size_t W_bytes      = align_up((size_t)krows * out_f * 4, 1024);
    size_t binned_bytes = align_up((size_t)nbins * nseg * SCAP * 4, 1024);   // 15.6 MB
    size_t part_bytes   = align_up((size_t)SLICES * 64 * PSTRIDE * 4, 1024); // 4.2 MB
    size_t union_bytes  = binned_bytes > part_bytes ? binned_bytes : part_bytes;
    size_t counts_bytes = align_up((size_t)NB * NSEGP * 4, 1024);            // 1 MB
    size_t ovf_bytes    = align_up((size_t)nseg * OVB * 8, 1024);            // ~125 KB
    size_t need_fast = W_bytes + union_bytes + counts_bytes + ovf_bytes + 1024;

    char* p = (char*)d_ws;
    float*    W       = (float*)p;
    unsigned* binned  = (unsigned*)(p + W_bytes);   // dead after bin_build
    float*    partial = (float*)(p + W_bytes);      // same region, used after
    int*      counts  = (int*)(p + W_bytes + union_bytes);
    int2*     ovfblk  = (int2*)(p + W_bytes + union_bytes + counts_bytes);

    const size_t sc_lds = (size_t)nbins * SCAP * 4;        // 32000 B @ nbins=500
    const size_t bb_lds = (size_t)ROWSB * out_f * 4;       // <= 32768 B
    const bool fast = (ws_size >= need_fast) && out_f <= 2048 && (out_f & 3) == 0 &&
                      krows <= 2048 && nbins <= NB - 1 && Bsz <= 64 && n_edges >= 1 &&
                      n_ot <= 32 && nseg <= NSEGP && sc_lds <= 64000 &&
                      bb_lds <= 32768 && (out_size & 3) == 0;

    if (fast) {
        smw_scatter14<<<nseg, TPB_SC, sc_lds, stream>>>(mask, wgt, binned, counts,
                                                        ovfblk, n_edges, krows,
                                                        nbins, nseg);
        smw_bin_build11<<<nbins, 512, bb_lds, stream>>>(binned, counts, ovfblk, W,
                                                        out_f, krows, nseg);
        dim3 grid(n_ot, SLICES);                           // 32 x 8
        smw_gemm7<<<grid, 256, 0, stream>>>(input, W, partial, in_features, out_f,
                                            krows, Bsz);
        int total4 = out_size >> 2;
        smw_reduce4<<<(total4 + 255) / 256, 256, 0, stream>>>(partial, bias, out,
                                                              out_f, Bsz, total4);
    } else {
        // round-1 known-good path (16 MB + flag)
        int* flag_fb = (int*)(p + (size_t)krows * out_f * 4);
        hipMemsetAsync(d_ws, 0, (size_t)krows * out_f * 4, stream);
        smw_detect<<<1, 64, 0, stream>>>((const unsigned int*)mask, flag_fb);
        smw_build_fb<<<(n_edges + 255) / 256, 256, 0, stream>>>(mask, wgt, W, flag_fb,
                                                                n_edges, out_f);
        smw_init_out_fb<<<(out_size + 255) / 256, 256, 0, stream>>>(out, bias, out_size, out_f);
        const int n_chunks = (krows + 31) / 32;
        dim3 grid((out_f + 63) / 64, 8);
        smw_gemm_fb<<<grid, 256, 0, stream>>>(input, W, out, in_features, out_f,
                                              krows, n_chunks, Bsz);
    }
}

// Round 18
// 49.349 us; speedup vs baseline: 1.1051x; 1.1051x over previous
//
#include <hip/hip_runtime.h>

// SparseMaskedLinear: out[b,co] = bias[co] + sum_e in[b,ci_e]*w_e  (B=64, dims 2000)
// Dense reformulation: W[ci][co] = sum w_e;  out = in[:, :2000] @ W + bias.
// Round-18: REVERT to round-14 verbatim (best measured: 49.48us). R15 (-staging),
// R16 (counts transpose), R17 (4-row bins + pipelined gemm) all neutral-to-worse;
// R14 is the plateau of this 4-dispatch pipeline shape.
// 4 dispatches: scatter(staged, 4B recs) -> bin_build -> gemm(prefetch) -> reduce.

#define ROWS8 8
#define NB 256                 // hist slots (nbins <= 250 gated)
#define NBP 256                // counts stride (blk-major); slot 255 = ovf count
#define SCAP 32                // slab capacity per (bin,blk); mean 16.4, +3.9 sigma
#define OVB 32                 // per-block overflow slab capacity
#define E_PT 8
#define TPB_SC 512
#define SEGX (TPB_SC * E_PT)   // 4096 edges per scatter block
#define PAD32 0xFFFFFFFFu      // bit 31 set = pad (valid keys have bit 31 clear)

#define TILE_O 64
#define KS 64
#define SLICES 16
#define PSTRIDE 2048

// ---- Phase 1: deterministic scatter, 4B records. Reg-preload 8 edges (MLP),
// LDS rank, flush used 32B granules of each 32-slot slab; blk-major counts.
// Overflow (r>=SCAP) -> per-block f32 slab, count in counts[blk][255].
__global__ __launch_bounds__(TPB_SC) void smw_scatter11(
    const int* __restrict__ mask, const float* __restrict__ wgt,
    unsigned* __restrict__ binned, int* __restrict__ counts,
    int2* __restrict__ ovfblk, int n_edges, int krows, int nbins, int nseg) {
    __shared__ int hist[NB];
    __shared__ int sflag;
    __shared__ int ovfc;
    extern __shared__ unsigned stage32[];      // nbins * SCAP u32 (<= 32000 B)
    const int tid = threadIdx.x;
    const int blk = blockIdx.x;
    const long long e0 = (long long)blk * SEGX;
    if (tid < NB) hist[tid] = 0;
    if (tid == 0) ovfc = 0;
    if (tid < 64) {
        unsigned v = (tid < n_edges) ? ((const unsigned*)mask)[2 * tid + 1] : 0u;
        unsigned long long bal = __ballot(v != 0u);
        if (tid == 0) sflag = (bal == 0ull) ? 1 : 0;   // high words all zero => int64
    }
    __syncthreads();
    const bool is64 = (sflag != 0);

    // load phase: 8 independent edges into registers (deep vmcnt pipeline)
    int ci[E_PT], co[E_PT]; float wv[E_PT];
    if (is64) {
        #pragma unroll
        for (int i = 0; i < E_PT; ++i) {
            long long e = e0 + (long long)i * TPB_SC + tid;
            ci[i] = -1; co[i] = 0;
            if (e < n_edges) { int4 mm = ((const int4*)mask)[e]; ci[i] = mm.x; co[i] = mm.z; }
        }
    } else {
        #pragma unroll
        for (int i = 0; i < E_PT; ++i) {
            long long e = e0 + (long long)i * TPB_SC + tid;
            ci[i] = -1; co[i] = 0;
            if (e < n_edges) { int2 mm = ((const int2*)mask)[e]; ci[i] = mm.x; co[i] = mm.y; }
        }
    }
    #pragma unroll
    for (int i = 0; i < E_PT; ++i) {
        long long e = e0 + (long long)i * TPB_SC + tid;
        wv[i] = (e < n_edges) ? wgt[e] : 0.0f;
    }

    // rank + stage phase (bf16 RNE pack)
    #pragma unroll
    for (int i = 0; i < E_PT; ++i) {
        if ((unsigned)ci[i] < (unsigned)krows) {
            int b = ci[i] >> 3;                    // 8 rows per bin
            int r = atomicAdd(&hist[b], 1);        // LDS rank
            if (r < SCAP) {
                unsigned u  = __float_as_uint(wv[i]);
                unsigned bf = (u + 0x7FFFu + ((u >> 16) & 1u)) >> 16;   // RNE
                unsigned key = (((unsigned)(ci[i] & 7)) << 11) | (unsigned)(co[i] & 0x7FF);
                stage32[b * SCAP + r] = (key << 16) | bf;
            } else {                               // rare tail (~10 records total)
                int j = atomicAdd(&ovfc, 1);
                if (j < OVB)
                    ovfblk[blk * OVB + j] =
                        make_int2((ci[i] << 16) | (co[i] & 0xFFFF),
                                  __float_as_int(wv[i]));
            }
        }
    }
    __syncthreads();
    // flush: 32 groups x 16 lanes, used 32B granules only
    const int grp = tid >> 4;
    const int ln  = tid & 15;
    for (int b = grp; b < nbins; b += (TPB_SC / 16)) {
        int c = hist[b]; if (c > SCAP) c = SCAP;
        int cp = (c + 7) & ~7;                     // 32B-granule padded count
        long long base = ((long long)b * nseg + blk) * SCAP;   // bin-major slabs
        for (int k = ln; k < cp; k += 16)
            binned[base + k] = (k < c) ? stage32[b * SCAP + k] : PAD32;
        if (ln == 0) counts[blk * NBP + b] = cp;   // blk-major -> coalesced line
    }
    if (tid == 0) {
        int oc = ovfc; if (oc > OVB) oc = OVB;
        counts[blk * NBP + (NBP - 1)] = oc;        // written EVERY call (stateless)
    }
}

// ---- Phase 2: per-bin exclusive build of 8 W-rows. Count-driven uint4 slab
// reads (4 records each), skip pad (bit31), LDS f32 atomics, float4 row stores.
__global__ __launch_bounds__(512) void smw_bin_build8(
    const unsigned* __restrict__ binned, const int* __restrict__ counts,
    const int2* __restrict__ ovfblk, float* __restrict__ W,
    int out_f, int krows, int nseg) {
    extern __shared__ float tile[];                 // ROWS8 * out_f floats
    const int tid = threadIdx.x;
    const int bin = blockIdx.x;
    const int tile_elems = ROWS8 * out_f;
    {
        float4* t4 = (float4*)tile;
        int n4 = tile_elems >> 2;
        for (int t = tid; t < n4; t += 512) t4[t] = make_float4(0.f, 0.f, 0.f, 0.f);
    }
    __syncthreads();
    const int grp = tid >> 3;                      // 64 subgroups of 8 lanes
    const int ln8 = tid & 7;
    for (int s = grp; s < nseg; s += 64) {
        int cp = counts[s * NBP + bin];            // uniform within subgroup
        const uint4* sp = (const uint4*)(binned + ((long long)bin * nseg + s) * SCAP);
        for (int j = ln8; j * 4 < cp; j += 8) {    // cp <= 32 -> one round
            uint4 q = sp[j];
            #pragma unroll
            for (int t = 0; t < 4; ++t) {
                unsigned r = (t == 0) ? q.x : (t == 1) ? q.y : (t == 2) ? q.z : q.w;
                if ((int)r >= 0) {                 // bit31 clear = valid
                    unsigned key = r >> 16;
                    atomicAdd(&tile[(int)(key >> 11) * out_f + (int)(key & 0x7FFu)],
                              __uint_as_float((r & 0xFFFFu) << 16));
                }
            }
        }
    }
    // per-block overflow slabs (expected ~10 records total, full f32)
    for (int s = tid; s < nseg; s += 512) {
        int oc = counts[s * NBP + (NBP - 1)];
        for (int j = 0; j < oc; ++j) {
            int2 r = ovfblk[s * OVB + j];
            int ci = ((unsigned)r.x) >> 16;
            if ((ci >> 3) == bin)
                atomicAdd(&tile[(ci & 7) * out_f + (r.x & 0xFFFF)],
                          __int_as_float(r.y));
        }
    }
    __syncthreads();
    #pragma unroll
    for (int r = 0; r < ROWS8; ++r) {
        int row = bin * ROWS8 + r;
        if (row >= krows) break;
        float* dst = W + (long long)row * out_f;
        const float* s = tile + r * out_f;
        for (int c = tid * 4; c < out_f; c += 2048)
            *(float4*)&dst[c] = *(const float4*)&s[c];
    }
}

// ---- staging helpers for gemm (static unroll, register-resident)
__device__ __forceinline__ void smw_load_a(float4 (&r)[4], const float* __restrict__ A,
                                           int k0, int in_features, int krows,
                                           int Bsz, int tid) {
    #pragma unroll
    for (int t = 0; t < 4; ++t) {
        int idx = t * 256 + tid;
        int b = idx >> 4;
        int c4 = (idx & 15) * 4;
        int gi = k0 + c4;
        float4 v = make_float4(0.f, 0.f, 0.f, 0.f);
        if (b < Bsz) {
            const float* src = A + (long long)b * in_features + gi;
            if (gi + 3 < krows) v = *(const float4*)src;
            else {
                if (gi + 0 < krows) v.x = src[0];
                if (gi + 1 < krows) v.y = src[1];
                if (gi + 2 < krows) v.z = src[2];
                if (gi + 3 < krows) v.w = src[3];
            }
        }
        r[t] = v;
    }
}

__device__ __forceinline__ void smw_load_w(float4 (&r)[4], const float* __restrict__ W,
                                           int k0, int o_base, int out_f, int krows,
                                           int tid) {
    #pragma unroll
    for (int t = 0; t < 4; ++t) {
        int idx = t * 256 + tid;
        int rr = idx >> 4;
        int c4 = (idx & 15) * 4;
        int gi = k0 + rr;
        int go = o_base + c4;
        float4 v = make_float4(0.f, 0.f, 0.f, 0.f);
        if (gi < krows) {
            const float* src = W + (long long)gi * out_f + go;
            if (go + 3 < out_f) v = *(const float4*)src;
            else {
                if (go + 0 < out_f) v.x = src[0];
                if (go + 1 < out_f) v.y = src[1];
                if (go + 2 < out_f) v.z = src[2];
                if (go + 3 < out_f) v.w = src[3];
            }
        }
        r[t] = v;
    }
}

// ---- Phase 3: GEMM with register prefetch of chunk 1 under chunk 0 compute.
__global__ __launch_bounds__(256) void smw_gemm6(
    const float* __restrict__ A, const float* __restrict__ W,
    float* __restrict__ partial, int in_features, int out_f, int krows, int Bsz) {
    __shared__ float As[64][KS + 4];
    __shared__ float Ws[KS][TILE_O];
    const int tid = threadIdx.x;
    const int tx = tid & 15;
    const int ty = tid >> 4;
    const int o_base = blockIdx.x * TILE_O;
    const int k0a = blockIdx.y * 2 * KS;
    const int k0b = k0a + KS;

    float4 ra[4], rw[4];
    smw_load_a(ra, A, k0a, in_features, krows, Bsz, tid);
    smw_load_w(rw, W, k0a, o_base, out_f, krows, tid);
    #pragma unroll
    for (int t = 0; t < 4; ++t) {
        int idx = t * 256 + tid;
        *(float4*)&As[idx >> 4][(idx & 15) * 4] = ra[t];
        *(float4*)&Ws[idx >> 4][(idx & 15) * 4] = rw[t];
    }
    smw_load_a(ra, A, k0b, in_features, krows, Bsz, tid);
    smw_load_w(rw, W, k0b, o_base, out_f, krows, tid);
    __syncthreads();

    float acc[4][4] = {};
    #pragma unroll 8
    for (int i = 0; i < KS; ++i) {
        float4 w4 = *(const float4*)&Ws[i][tx * 4];
        float a[4];
        #pragma unroll
        for (int r = 0; r < 4; ++r) a[r] = As[ty * 4 + r][i];
        #pragma unroll
        for (int r = 0; r < 4; ++r) {
            acc[r][0] += a[r] * w4.x;
            acc[r][1] += a[r] * w4.y;
            acc[r][2] += a[r] * w4.z;
            acc[r][3] += a[r] * w4.w;
        }
    }
    __syncthreads();
    #pragma unroll
    for (int t = 0; t < 4; ++t) {
        int idx = t * 256 + tid;
        *(float4*)&As[idx >> 4][(idx & 15) * 4] = ra[t];
        *(float4*)&Ws[idx >> 4][(idx & 15) * 4] = rw[t];
    }
    __syncthreads();
    #pragma unroll 8
    for (int i = 0; i < KS; ++i) {
        float4 w4 = *(const float4*)&Ws[i][tx * 4];
        float a[4];
        #pragma unroll
        for (int r = 0; r < 4; ++r) a[r] = As[ty * 4 + r][i];
        #pragma unroll
        for (int r = 0; r < 4; ++r) {
            acc[r][0] += a[r] * w4.x;
            acc[r][1] += a[r] * w4.y;
            acc[r][2] += a[r] * w4.z;
            acc[r][3] += a[r] * w4.w;
        }
    }

    float* P = partial + (long long)blockIdx.y * 64 * PSTRIDE;
    #pragma unroll
    for (int r = 0; r < 4; ++r) {
        int b = ty * 4 + r;
        if (b < Bsz)
            *(float4*)&P[(long long)b * PSTRIDE + o_base + tx * 4] =
                make_float4(acc[r][0], acc[r][1], acc[r][2], acc[r][3]);
    }
}

// ---- Phase 4: out = bias + sum_s partial[s]  (float4 lanes)
__global__ void smw_reduce3(const float* __restrict__ partial,
                            const float* __restrict__ bias,
                            float* __restrict__ out, int out_f, int Bsz, int total4) {
    int idx = blockIdx.x * blockDim.x + threadIdx.x;
    if (idx >= total4) return;
    const int of4 = out_f >> 2;
    int b = idx / of4, o4 = idx - b * of4;
    const float4* B4 = (const float4*)bias;
    const float4* P4 = (const float4*)partial;
    float4 acc = B4[o4];
    #pragma unroll
    for (int s = 0; s < SLICES; ++s) {
        float4 v = P4[((long long)s * 64 + b) * (PSTRIDE >> 2) + o4];
        acc.x += v.x; acc.y += v.y; acc.z += v.z; acc.w += v.w;
    }
    ((float4*)out)[idx] = acc;
}

// ================= fallback path (round-1, known-good, needs only 16 MB ws) ==
__global__ void smw_detect(const unsigned int* __restrict__ m, int* __restrict__ flag) {
    if (blockIdx.x == 0 && threadIdx.x == 0) {
        unsigned int orv = 0u;
        for (int k = 0; k < 64; ++k) orv |= m[2 * k + 1];
        *flag = (orv == 0u) ? 1 : 0;
    }
}

__global__ void smw_build_fb(const int* __restrict__ mask, const float* __restrict__ wgt,
                             float* __restrict__ W, const int* __restrict__ flag,
                             int n_edges, int out_f) {
    int e = blockIdx.x * blockDim.x + threadIdx.x;
    if (e >= n_edges) return;
    int ci, co;
    if (*flag) {
        const long long* m64 = (const long long*)mask;
        ci = (int)m64[2 * (long long)e];
        co = (int)m64[2 * (long long)e + 1];
    } else {
        ci = mask[2 * e]; co = mask[2 * e + 1];
    }
    atomicAdd(&W[(long long)ci * out_f + co], wgt[e]);
}

__global__ void smw_init_out_fb(float* __restrict__ out, const float* __restrict__ bias,
                                int total, int out_f) {
    int idx = blockIdx.x * blockDim.x + threadIdx.x;
    if (idx < total) out[idx] = bias[idx % out_f];
}

__global__ __launch_bounds__(256) void smw_gemm_fb(
    const float* __restrict__ A, const float* __restrict__ W,
    float* __restrict__ out, int in_features, int out_f, int krows,
    int n_chunks, int Bsz) {
    __shared__ float As[64][36];
    __shared__ float Ws[32][64];
    const int tid = threadIdx.x;
    const int tx = tid & 15;
    const int ty = tid >> 4;
    const int o_base = blockIdx.x * 64;
    float acc[4][4] = {};
    for (int c = blockIdx.y; c < n_chunks; c += 8) {
        const int i0 = c * 32;
        __syncthreads();
        #pragma unroll
        for (int k = 0; k < 8; ++k) {
            int idx = k * 256 + tid;
            int i = idx & 31;
            int b = idx >> 5;
            float v = 0.0f;
            int gi = i0 + i;
            if (b < Bsz && gi < in_features) v = A[(long long)b * in_features + gi];
            As[b][i] = v;
        }
        #pragma unroll
        for (int k = 0; k < 8; ++k) {
            int idx = k * 256 + tid;
            int o = idx & 63;
            int i = idx >> 6;
            int gi = i0 + i;
            int go = o_base + o;
            Ws[i][o] = (gi < krows && go < out_f) ? W[(long long)gi * out_f + go] : 0.0f;
        }
        __syncthreads();
        #pragma unroll
        for (int i = 0; i < 32; ++i) {
            float4 w4 = *(const float4*)(&Ws[i][tx * 4]);
            float a[4];
            #pragma unroll
            for (int r = 0; r < 4; ++r) a[r] = As[ty * 4 + r][i];
            #pragma unroll
            for (int r = 0; r < 4; ++r) {
                acc[r][0] += a[r] * w4.x;
                acc[r][1] += a[r] * w4.y;
                acc[r][2] += a[r] * w4.z;
                acc[r][3] += a[r] * w4.w;
            }
        }
    }
    #pragma unroll
    for (int r = 0; r < 4; ++r) {
        int b = ty * 4 + r;
        if (b >= Bsz) continue;
        #pragma unroll
        for (int cc = 0; cc < 4; ++cc) {
            int o = o_base + tx * 4 + cc;
            if (o < out_f) atomicAdd(&out[(long long)b * out_f + o], acc[r][cc]);
        }
    }
}

// =============================================================================
static inline size_t align_up(size_t x, size_t a) { return (x + a - 1) & ~(a - 1); }

extern "C" void kernel_launch(void* const* d_in, const int* in_sizes, int n_in,
                              void* d_out, int out_size, void* d_ws, size_t ws_size,
                              hipStream_t stream) {
    const float* input = (const float*)d_in[0];
    const int*   mask  = (const int*)d_in[1];
    const float* wgt   = (const float*)d_in[2];
    const float* bias  = (const float*)d_in[3];
    float* out = (float*)d_out;

    const int out_f   = in_sizes[3];            // 2000
    const int n_edges = in_sizes[2];            // 2,000,000
    const int Bsz     = out_size / out_f;       // 64
    const int in_features = in_sizes[0] / Bsz;  // 20000
    const int krows   = out_f;                  // ci values < out_f per problem spec
    const int nbins   = (krows + ROWS8 - 1) / ROWS8;   // 250
    const int nseg    = (n_edges + SEGX - 1) / SEGX;   // 489
    const int n_ot    = (out_f + TILE_O - 1) / TILE_O; // 32

    size_t W_bytes      = align_up((size_t)krows * out_f * 4, 1024);
    size_t binned_bytes = align_up((size_t)nbins * nseg * SCAP * 4, 1024);   // 15.6 MB
    size_t part_bytes   = align_up((size_t)SLICES * 64 * PSTRIDE * 4, 1024); // 8.4 MB
    size_t union_bytes  = binned_bytes > part_bytes ? binned_bytes : part_bytes;
    size_t counts_bytes = align_up((size_t)nseg * NBP * 4, 1024);            // ~500 KB
    size_t ovf_bytes    = align_up((size_t)nseg * OVB * 8, 1024);            // ~125 KB
    size_t need_fast = W_bytes + union_bytes + counts_bytes + ovf_bytes + 1024;

    char* p = (char*)d_ws;
    float*    W       = (float*)p;
    unsigned* binned  = (unsigned*)(p + W_bytes);   // dead after bin_build
    float*    partial = (float*)(p + W_bytes);      // same region, used after
    int*      counts  = (int*)(p + W_bytes + union_bytes);
    int2*     ovfblk  = (int2*)(p + W_bytes + union_bytes + counts_bytes);

    const size_t sc_lds = (size_t)nbins * SCAP * 4;        // 32000 B @ nbins=250
    const size_t bb_lds = (size_t)ROWS8 * out_f * 4;       // <= 64000 B
    const bool fast = (ws_size >= need_fast) && out_f <= 2048 && (out_f & 3) == 0 &&
                      krows <= 2048 && nbins <= 250 && Bsz <= 64 && n_edges >= 1 &&
                      n_ot <= 32 && sc_lds <= 64000 && bb_lds <= 65536 &&
                      (out_size & 3) == 0;

    if (fast) {
        smw_scatter11<<<nseg, TPB_SC, sc_lds, stream>>>(mask, wgt, binned, counts,
                                                        ovfblk, n_edges, krows,
                                                        nbins, nseg);
        smw_bin_build8<<<nbins, 512, bb_lds, stream>>>(binned, counts, ovfblk, W,
                                                       out_f, krows, nseg);
        dim3 grid(n_ot, SLICES);                           // 32 x 16
        smw_gemm6<<<grid, 256, 0, stream>>>(input, W, partial, in_features, out_f,
                                            krows, Bsz);
        int total4 = out_size >> 2;
        smw_reduce3<<<(total4 + 255) / 256, 256, 0, stream>>>(partial, bias, out,
                                                              out_f, Bsz, total4);
    } else {
        // round-1 known-good path (16 MB + flag)
        int* flag_fb = (int*)(p + (size_t)krows * out_f * 4);
        hipMemsetAsync(d_ws, 0, (size_t)krows * out_f * 4, stream);
        smw_detect<<<1, 64, 0, stream>>>((const unsigned int*)mask, flag_fb);
        smw_build_fb<<<(n_edges + 255) / 256, 256, 0, stream>>>(mask, wgt, W, flag_fb,
                                                                n_edges, out_f);
        smw_init_out_fb<<<(out_size + 255) / 256, 256, 0, stream>>>(out, bias, out_size, out_f);
        const int n_chunks = (krows + 31) / 32;
        dim3 grid((out_f + 63) / 64, 8);
        smw_gemm_fb<<<grid, 256, 0, stream>>>(input, W, out, in_features, out_f,
                                              krows, n_chunks, Bsz);
    }
}